// Round 1
// baseline (104.084 us; speedup 1.0000x reference)
//
#include <hip/hip_runtime.h>

// Problem constants (from reference setup_inputs): B=2, H=W=128.
#define B_ITEMS 2
#define W_IMG   128
#define N_PTS   16384          // H*W
#define CH_GRID 2048           // = max Utot = 2 halves * 4 * ceil(16384/64)
#define BIGF    3.4e38f

// ---------------------------------------------------------------------------
// Kernel 1: compaction (R7 structure, proven correct & fast) + one addition:
// each of the 65536 prep threads initializes one rmG slot to +BIG (rmG is the
// per-row global min table the column-split chamfer units atomicMin into).
//   raw[pos] = (x, y, z, |q|^2)        row side
//   tf [pos] = (-2x, -2y, -2z, |q|^2)  col side: d = |p|^2 + fma3(p, tf)
// Block 0/tid 0 zeroes out[0] (stream order precedes finish's atomicAdds).
// ---------------------------------------------------------------------------
__global__ __launch_bounds__(256) void prep_kernel(
        const float* __restrict__ pred,
        const float* __restrict__ gt,
        const int*   __restrict__ mask,
        const float* fxp, const float* fyp,
        const float* cxp, const float* cyp,
        int*    __restrict__ cnt,       // [0]=np0 [1]=np1 [2]=ng0 [3]=ng1
        float4* __restrict__ pR, float4* __restrict__ gR,   // raw   [B][N]
        float4* __restrict__ pT, float4* __restrict__ gT,   // transf[B][N]
        float*  __restrict__ rmG,       // [4][N_PTS] per-row min table
        float*  __restrict__ out) {
    int s    = blockIdx.x >> 6;
    int b    = s & 1;
    int isG  = s >> 1;
    int tid  = threadIdx.x;
    int idx  = (blockIdx.x & 63) * 256 + tid;
    int lane = tid & 63, w = tid >> 6;

    if (blockIdx.x == 0 && tid == 0) out[0] = 0.0f;
    // 256 blocks x 256 threads == 65536 == 4 * N_PTS: init the min table.
    rmG[(blockIdx.x << 8) + tid] = BIGF;

    float x, y, z;
    if (!isG) {
        float fx = *fxp, fy = *fyp, cx = *cxp, cy = *cyp;
        float u = (float)(idx & (W_IMG - 1));
        float v = (float)(idx >> 7);
        z = pred[b * N_PTS + idx];
        x = (u - cx) / fx * z;
        y = (v - cy) / fy * z;
    } else {
        x = gt[(b * 3 + 0) * N_PTS + idx];
        y = gt[(b * 3 + 1) * N_PTS + idx];
        z = gt[(b * 3 + 2) * N_PTS + idx];
    }
    int  mv = mask[b * N_PTS + idx];
    bool ok = (mv > 0) && (((x + y) + z) != 0.0f);

    unsigned long long bal = __ballot(ok);
    int nw  = __popcll(bal);
    int pre = __popcll(bal & ((1ull << lane) - 1ull));

    __shared__ int wbase[4];
    __shared__ int blockbase;
    if (lane == 0) wbase[w] = nw;
    __syncthreads();
    if (tid == 0) {
        int s0 = 0;
#pragma unroll
        for (int i = 0; i < 4; ++i) { int t = wbase[i]; wbase[i] = s0; s0 += t; }
        blockbase = s0 ? atomicAdd(&cnt[s], s0) : 0;
    }
    __syncthreads();

    if (ok) {
        int pos = blockbase + wbase[w] + pre;
        float ps = fmaf(z, z, fmaf(y, y, x * x));
        float4* __restrict__ raw = (isG ? gR : pR) + b * N_PTS;
        float4* __restrict__ tf  = (isG ? gT : pT) + b * N_PTS;
        raw[pos] = make_float4(x, y, z, ps);
        tf[pos]  = make_float4(-2.0f * x, -2.0f * y, -2.0f * z, ps);
    }
}

// ---------------------------------------------------------------------------
// Kernel 2: direct-sum chamfer. R12 deltas vs the 103.3 us version:
//  (a) COLUMN-SPLIT: each 64-row unit is split into 2 column-halves ->
//      1024 active blocks (4/CU, 4 waves/SIMD) instead of 512 (2/CU).
//      LDS bytes/pair unchanged (2 B) so the LDS pipe stays unsaturated
//      (~73 B/cyc/CU at full VALU vs ~85-128 capacity). Cross-half combine
//      via atomicMin on int-viewed nonneg floats into rmG[s][row]
//      (max(min,0) == min(max(.,0)), both monotone -> exact).
//  (b) TWO COLS/ITER + v_min3_f32: fminf(fminf(rm,d0),d1) fuses to min3:
//      7 VALU ops per 2 pairs vs 8 (floor 13.7 -> 12.0 us). Pair cols sit
//      32 float4-slots apart so each b128 keeps the conflict-free
//      16 B/lane stride (paired-adjacent layout would be 4-way conflicted).
//  (c) Unconditional staging for full tiles (mask/clamp only on the ragged
//      last tile of a half).
// Thread layout unchanged: 8 rows/thread (R11: 16 rows starves VGPRs;
// 4 rows doubles LDS/pair into the pipe limit).
// ---------------------------------------------------------------------------
__global__ __launch_bounds__(256, 4) void chamfer_kernel(
        const int*    __restrict__ cnt,
        const float4* __restrict__ pR, const float4* __restrict__ gR,
        const float4* __restrict__ pT, const float4* __restrict__ gT,
        float* __restrict__ rmG) {
    int np0 = cnt[0], np1 = cnt[1], ng0 = cnt[2], ng1 = cnt[3];
    int naArr[4] = {np0, ng0, np1, ng1};
    int nbArr[4] = {ng0, np0, ng1, np1};
    const float4* Arow[4] = {pR, gR, pR + N_PTS, gR + N_PTS};
    const float4* Bcol[4] = {gT, pT, gT + N_PTS, pT + N_PTS};

    int units[4];
    int Utot = 0;
#pragma unroll
    for (int i = 0; i < 4; ++i) {
        units[i] = (naArr[i] > 0 && nbArr[i] > 0) ? (2 * ((naArr[i] + 63) >> 6)) : 0;
        Utot += units[i];
    }
    int u = blockIdx.x;
    if (u >= Utot) return;
    int s = 0;
    while (u >= units[s]) { u -= units[s]; ++s; }
    int na = naArr[s], nb = nbArr[s];
    const float4* __restrict__ A  = Arow[s];
    const float4* __restrict__ Bp = Bcol[s];
    int h       = u & 1;                 // column half
    int rowbase = (u >> 1) * 64;
    int half    = (nb + 1) >> 1;
    int cbase   = h * half;
    int ccount  = min(nb - cbase, half); // >= 0 (0 possible when nb==1,h==1)

    int tid = threadIdx.x;
    int tc = tid & 31, tr = tid >> 5;

    // 8 rows/thread: row = rowbase + a*8 + tr (rows >= na gated at the end;
    // ws poison 0xAA reads as ~-3e-13, finite -> no NaN/Inf hazard).
    float px[8], py[8], pz[8], rm[8];
#pragma unroll
    for (int a = 0; a < 8; ++a) {
        float4 v = A[rowbase + a * 8 + tr];      // < N_PTS capacity always
        px[a] = v.x; py[a] = v.y; pz[a] = v.z;
        rm[a] = BIGF;
    }

    __shared__ float4 sB[2][512];                // 512-col tiles, dbuf (16 KB)
    int ntiles = (ccount + 511) >> 9;            // can be 0 (empty half)

    // stage tile 0 (fast path when full; branchless masked otherwise)
    if (512 <= ccount) {
#pragma unroll
        for (int k = 0; k < 2; ++k)
            sB[0][k * 256 + tid] = Bp[cbase + k * 256 + tid];
    } else {
#pragma unroll
        for (int k = 0; k < 2; ++k) {
            int j = k * 256 + tid;
            float4 v = Bp[min(cbase + j, N_PTS - 1)];
            bool okc = j < ccount;
            float4 r;
            r.x = okc ? v.x : 0.0f;
            r.y = okc ? v.y : 0.0f;
            r.z = okc ? v.z : 0.0f;
            r.w = okc ? v.w : BIGF;              // sentinel col never wins min
            sB[0][k * 256 + tid] = r;
        }
    }
    __syncthreads();

    for (int t = 0; t < ntiles; ++t) {
        float4 r0, r1;                           // prefetch tile t+1 (global)
        bool have = (t + 1 < ntiles);
        if (have) {
            int j0 = (t + 1) * 512 + tid;
            int j1 = j0 + 256;
            if ((t + 2) * 512 <= ccount) {       // next tile is full
                r0 = Bp[cbase + j0];
                r1 = Bp[cbase + j1];
            } else {
                float4 v0 = Bp[min(cbase + j0, N_PTS - 1)];
                float4 v1 = Bp[min(cbase + j1, N_PTS - 1)];
                bool k0 = j0 < ccount, k1 = j1 < ccount;
                r0.x = k0 ? v0.x : 0.0f; r0.y = k0 ? v0.y : 0.0f;
                r0.z = k0 ? v0.z : 0.0f; r0.w = k0 ? v0.w : BIGF;
                r1.x = k1 ? v1.x : 0.0f; r1.y = k1 ? v1.y : 0.0f;
                r1.z = k1 ? v1.z : 0.0f; r1.w = k1 ? v1.w : BIGF;
            }
        }
        const float4* __restrict__ bufc = sB[t & 1] + tc;
#pragma unroll
        for (int cb = 0; cb < 8; ++cb) {
            float4 c0 = bufc[cb * 64];           // 16 B/lane stride: no conflict
            float4 c1 = bufc[cb * 64 + 32];
#pragma unroll
            for (int a = 0; a < 8; ++a) {
                float d0 = fmaf(px[a], c0.x,
                              fmaf(py[a], c0.y, fmaf(pz[a], c0.z, c0.w)));
                float d1 = fmaf(px[a], c1.x,
                              fmaf(py[a], c1.y, fmaf(pz[a], c1.z, c1.w)));
                rm[a] = fminf(fminf(rm[a], d0), d1);   // -> v_min3_f32
            }
        }
        if (have) {
            sB[(t + 1) & 1][tid] = r0;
            sB[(t + 1) & 1][256 + tid] = r1;
        }
        __syncthreads();                          // readers done + write visible
    }

    // fold over tc (lane bits 0..4)
#pragma unroll
    for (int a = 0; a < 8; ++a) {
        float v = rm[a];
        v = fminf(v, __shfl_xor(v, 1, 64));
        v = fminf(v, __shfl_xor(v, 2, 64));
        v = fminf(v, __shfl_xor(v, 4, 64));
        v = fminf(v, __shfl_xor(v, 8, 64));
        v = fminf(v, __shfl_xor(v, 16, 64));
        rm[a] = v;
    }
    if (tc == 0) {                               // lanes 0 & 32 of each wave
        int base = s << 14;
#pragma unroll
        for (int a = 0; a < 8; ++a) {
            int row = rowbase + a * 8 + tr;
            if (row < na) {
                float ps = A[row].w;             // |p|^2 (L1-hot reload)
                float vr = fmaxf(rm[a] + ps, 0.0f);   // nonneg -> int order ok
                atomicMin((int*)&rmG[base + row], __float_as_int(vr));
            }
        }
    }
}

// ---------------------------------------------------------------------------
// Kernel 3: sum the per-row mins (valid rows only) into out. 65536 threads,
// one value each; wave reduce + one atomicAdd per block.
// ---------------------------------------------------------------------------
__global__ __launch_bounds__(256) void finish_kernel(
        const int*   __restrict__ cnt,
        const float* __restrict__ rmG,
        float*       __restrict__ out) {
    int gid = blockIdx.x * 256 + threadIdx.x;    // 256 blocks x 256
    int s   = gid >> 14;
    int row = gid & (N_PTS - 1);
    int np0 = cnt[0], np1 = cnt[1], ng0 = cnt[2], ng1 = cnt[3];
    int naArr[4] = {np0, ng0, np1, ng1};
    int nbArr[4] = {ng0, np0, ng1, np1};
    float v = (row < naArr[s] && nbArr[s] > 0) ? rmG[gid] : 0.0f;
#pragma unroll
    for (int off = 32; off > 0; off >>= 1)
        v += __shfl_down(v, off, 64);
    __shared__ float wsum[4];
    if ((threadIdx.x & 63) == 0) wsum[threadIdx.x >> 6] = v;
    __syncthreads();
    if (threadIdx.x == 0) {
        float t = (wsum[0] + wsum[1]) + (wsum[2] + wsum[3]);
        atomicAdd(out, t * (1.0f / B_ITEMS));
    }
}

extern "C" void kernel_launch(void* const* d_in, const int* in_sizes, int n_in,
                              void* d_out, int out_size, void* d_ws, size_t ws_size,
                              hipStream_t stream) {
    const float* pred = (const float*)d_in[0];
    const float* gt   = (const float*)d_in[1];
    const int*   mask = (const int*)  d_in[2];
    const float* fx   = (const float*)d_in[3];
    const float* fy   = (const float*)d_in[4];
    const float* cx   = (const float*)d_in[5];
    const float* cy   = (const float*)d_in[6];
    float* out = (float*)d_out;

    // ws: [0,256) cnt | pR 512K | gR 512K | pT 512K | gT 512K | rmG 256K
    char* ws = (char*)d_ws;
    size_t SEG = (size_t)B_ITEMS * N_PTS * 16;
    int*    cnt = (int*)ws;
    float4* pR  = (float4*)(ws + 256);
    float4* gR  = (float4*)(ws + 256 + SEG);
    float4* pT  = (float4*)(ws + 256 + 2 * SEG);
    float4* gT  = (float4*)(ws + 256 + 3 * SEG);
    float*  rmG = (float*) (ws + 256 + 4 * SEG);

    hipMemsetAsync(cnt, 0, 16, stream);

    prep_kernel<<<dim3(256), 256, 0, stream>>>(
        pred, gt, mask, fx, fy, cx, cy, cnt, pR, gR, pT, gT, rmG, out);

    chamfer_kernel<<<dim3(CH_GRID), 256, 0, stream>>>(
        cnt, pR, gR, pT, gT, rmG);

    finish_kernel<<<dim3(256), 256, 0, stream>>>(cnt, rmG, out);
}